// Round 4
// baseline (142.009 us; speedup 1.0000x reference)
//
#include <hip/hip_runtime.h>

// Problem dims (fixed by reference)
#define B_DIM 32
#define N_DIM 4096
#define PATCH_DIM 1024
#define TEXT_DIM 768
#define HIDDEN 512

typedef float f32x4 __attribute__((ext_vector_type(4)));

__device__ __forceinline__ float dot4(f32x4 a, f32x4 b) {
    return a.x * b.x + a.y * b.y + a.z * b.z + a.w * b.w;
}

// ---------------------------------------------------------------------------
// Prep kernel (fused A+B): grid (32 b, 4 d-chunks), 256 threads.
// Phase 1: every block computes t[b,:] = text[b]·W_text^T + b_text into LDS
//          (redundant across the 4 dc-blocks; ~1.3 us, W_text L2-resident).
// Phase 2: block (b,dc) computes v[b, dc*256 + tid] = sum_h t[h]*W_patch[h,d].
//          dc==0 blocks also compute bias[b] = t[b,:]·b_patch.
// ---------------------------------------------------------------------------
__global__ __launch_bounds__(256) void prep_kernel(
    const float* __restrict__ text,     // [B, TEXT_DIM]
    const float* __restrict__ W_text,   // [HIDDEN, TEXT_DIM]
    const float* __restrict__ b_text,   // [HIDDEN]
    const float* __restrict__ W_patch,  // [HIDDEN, PATCH_DIM]
    const float* __restrict__ b_patch,  // [HIDDEN]
    float* __restrict__ v,              // [B, PATCH_DIM]
    float* __restrict__ bias_out)       // [B]
{
    const int b   = blockIdx.x;
    const int dc  = blockIdx.y;
    const int tid = threadIdx.x;

    __shared__ float t_sh[HIDDEN];

    // ---- Phase 1: t_sh[h] for h = tid, tid+256 ----
    const f32x4* tx4 = (const f32x4*)(text + (size_t)b * TEXT_DIM);
    #pragma unroll
    for (int hh = 0; hh < 2; ++hh) {
        const int h = tid + hh * 256;
        const f32x4* w = (const f32x4*)(W_text + (size_t)h * TEXT_DIM);
        f32x4 acc0 = {0,0,0,0}, acc1 = {0,0,0,0};
        #pragma unroll 4
        for (int j = 0; j < TEXT_DIM / 4; j += 2) {
            f32x4 a0 = tx4[j],     w0 = w[j];
            f32x4 a1 = tx4[j + 1], w1 = w[j + 1];
            acc0.x += a0.x * w0.x; acc0.y += a0.y * w0.y;
            acc0.z += a0.z * w0.z; acc0.w += a0.w * w0.w;
            acc1.x += a1.x * w1.x; acc1.y += a1.y * w1.y;
            acc1.z += a1.z * w1.z; acc1.w += a1.w * w1.w;
        }
        t_sh[h] = (acc0.x + acc0.y) + (acc0.z + acc0.w)
                + (acc1.x + acc1.y) + (acc1.z + acc1.w) + b_text[h];
    }
    __syncthreads();

    // ---- Phase 2: one output column d per thread ----
    const int d = dc * 256 + tid;
    const float* wp = W_patch + d;
    float a0 = 0.f, a1 = 0.f, a2 = 0.f, a3 = 0.f;
    #pragma unroll 4
    for (int h = 0; h < HIDDEN; h += 4) {
        a0 = fmaf(t_sh[h + 0], wp[(size_t)(h + 0) * PATCH_DIM], a0);
        a1 = fmaf(t_sh[h + 1], wp[(size_t)(h + 1) * PATCH_DIM], a1);
        a2 = fmaf(t_sh[h + 2], wp[(size_t)(h + 2) * PATCH_DIM], a2);
        a3 = fmaf(t_sh[h + 3], wp[(size_t)(h + 3) * PATCH_DIM], a3);
    }
    v[(size_t)b * PATCH_DIM + d] = (a0 + a1) + (a2 + a3);

    if (dc == 0) {
        float partial = t_sh[tid] * b_patch[tid]
                      + t_sh[tid + 256] * b_patch[tid + 256];
        #pragma unroll
        for (int off = 32; off; off >>= 1)
            partial += __shfl_xor(partial, off, 64);
        __shared__ float wsum[4];
        if ((tid & 63) == 0) wsum[tid >> 6] = partial;
        __syncthreads();
        if (tid == 0)
            bias_out[b] = (wsum[0] + wsum[1]) + (wsum[2] + wsum[3]);
    }
}

// ---------------------------------------------------------------------------
// Kernel C (dominant, streams 512 MB of patches):
//   scores[b,n] = patches[b,n,:] . v[b,:] + bias[b]
// R2's work mapping (proven best so far): 2048 blocks x 4 waves, wave owns 16
// contiguous rows of one b, v[b] in 16 registers for the wave's lifetime.
// NEW: explicit two-stage double-buffered pipeline — group g+1's 16
// nontemporal loads are issued BEFORE group g's dot/butterfly/store, so the
// wave keeps ~16 KB outstanding through the reduce tail. (R3's regression was
// `#pragma unroll 1` destroying exactly this MLP; R2 relied on the compiler
// finding it implicitly.)
// ---------------------------------------------------------------------------
__device__ __forceinline__ void load_group(
    const float* __restrict__ patches, int row, int lane, f32x4 (&A)[16]) {
    #pragma unroll
    for (int r = 0; r < 4; ++r) {
        const f32x4* p = (const f32x4*)(patches + (size_t)(row + r) * PATCH_DIM);
        #pragma unroll
        for (int k = 0; k < 4; ++k)
            A[r * 4 + k] = __builtin_nontemporal_load(p + lane + 64 * k);
    }
}

__device__ __forceinline__ void reduce_store_group(
    const f32x4 (&A)[16], const f32x4 (&V)[4], float bs,
    float* __restrict__ out, int row, int lane) {
    float s0 = dot4(A[0], V[0]) + dot4(A[1], V[1]) + dot4(A[2], V[2]) + dot4(A[3], V[3]);
    float s1 = dot4(A[4], V[0]) + dot4(A[5], V[1]) + dot4(A[6], V[2]) + dot4(A[7], V[3]);
    float s2 = dot4(A[8], V[0]) + dot4(A[9], V[1]) + dot4(A[10], V[2]) + dot4(A[11], V[3]);
    float s3 = dot4(A[12], V[0]) + dot4(A[13], V[1]) + dot4(A[14], V[2]) + dot4(A[15], V[3]);

    #pragma unroll
    for (int off = 32; off; off >>= 1) {
        s0 += __shfl_xor(s0, off, 64);
        s1 += __shfl_xor(s1, off, 64);
        s2 += __shfl_xor(s2, off, 64);
        s3 += __shfl_xor(s3, off, 64);
    }
    if (lane == 0) {
        f32x4 o = { s0 + bs, s1 + bs, s2 + bs, s3 + bs };
        *(f32x4*)(out + row) = o;
    }
}

__global__ __launch_bounds__(256) void score_kernel(
    const float* __restrict__ patches,  // [B*N, PATCH_DIM]
    const float* __restrict__ v,        // [B, PATCH_DIM]
    const float* __restrict__ bias,     // [B]
    float* __restrict__ out)            // [B*N]
{
    const int lane = threadIdx.x & 63;
    const int g    = blockIdx.x * 4 + (threadIdx.x >> 6);  // 0..8191
    const int b    = g >> 8;            // 256 waves per b
    const int row0 = g << 4;            // 16 rows per wave

    const f32x4* vv = (const f32x4*)(v + (size_t)b * PATCH_DIM);
    f32x4 V[4];
    #pragma unroll
    for (int k = 0; k < 4; ++k) V[k] = vv[lane + 64 * k];
    const float bs = bias[b];

    f32x4 bufA[16], bufB[16];

    // Pipeline: load(g+1) issued before reduce(g). Static register names
    // throughout (no runtime-indexed buffers -> no scratch).
    load_group(patches, row0 + 0, lane, bufA);
    load_group(patches, row0 + 4, lane, bufB);
    reduce_store_group(bufA, V, bs, out, row0 + 0, lane);
    load_group(patches, row0 + 8, lane, bufA);
    reduce_store_group(bufB, V, bs, out, row0 + 4, lane);
    load_group(patches, row0 + 12, lane, bufB);
    reduce_store_group(bufA, V, bs, out, row0 + 8, lane);
    reduce_store_group(bufB, V, bs, out, row0 + 12, lane);
}

extern "C" void kernel_launch(void* const* d_in, const int* in_sizes, int n_in,
                              void* d_out, int out_size, void* d_ws, size_t ws_size,
                              hipStream_t stream) {
    const float* patches = (const float*)d_in[0];  // [B, N, PATCH_DIM]
    const float* text    = (const float*)d_in[1];  // [B, TEXT_DIM]
    const float* W_patch = (const float*)d_in[2];  // [HIDDEN, PATCH_DIM]
    const float* b_patch = (const float*)d_in[3];  // [HIDDEN]
    const float* W_text  = (const float*)d_in[4];  // [HIDDEN, TEXT_DIM]
    const float* b_text  = (const float*)d_in[5];  // [HIDDEN]
    float* out = (float*)d_out;                    // [B, N]

    // Workspace layout (floats): v [B*PATCH_DIM], bias [B]
    float* v_ws    = (float*)d_ws;
    float* bias_ws = v_ws + B_DIM * PATCH_DIM;

    prep_kernel<<<dim3(B_DIM, 4), 256, 0, stream>>>(text, W_text, b_text,
                                                    W_patch, b_patch,
                                                    v_ws, bias_ws);
    score_kernel<<<2048, 256, 0, stream>>>(patches, v_ws, bias_ws, out);
}

// Round 5
// 126.565 us; speedup vs baseline: 1.1220x; 1.1220x over previous
//
#include <hip/hip_runtime.h>

// Problem dims (fixed by reference)
#define B_DIM 32
#define N_DIM 4096
#define PATCH_DIM 1024
#define TEXT_DIM 768
#define HIDDEN 512

typedef float f32x4 __attribute__((ext_vector_type(4)));

__device__ __forceinline__ float dot4(f32x4 a, f32x4 b) {
    return a.x * b.x + a.y * b.y + a.z * b.z + a.w * b.w;
}

// ---------------------------------------------------------------------------
// Kernel A: t[b,h] = text[b,:] . W_text[h,:] + b_text[h]
// grid (32 b, 8 h-chunks), 256 threads. One wave per 16 h-values; text row
// (768 floats = 3 f32x4/lane) cached in registers across the h loop.
// (R2-proven; unchanged.)
// ---------------------------------------------------------------------------
__global__ __launch_bounds__(256) void text_proj_kernel(
    const float* __restrict__ text,     // [B, TEXT_DIM]
    const float* __restrict__ W_text,   // [HIDDEN, TEXT_DIM]
    const float* __restrict__ b_text,   // [HIDDEN]
    float* __restrict__ t_out)          // [B, HIDDEN]
{
    const int b    = blockIdx.x;
    const int lane = threadIdx.x & 63;
    const int hbase = blockIdx.y * 64 + (threadIdx.x >> 6) * 16;

    const f32x4* tx4 = (const f32x4*)(text + (size_t)b * TEXT_DIM);
    const f32x4 t0 = tx4[lane], t1 = tx4[lane + 64], t2 = tx4[lane + 128];

    #pragma unroll 2
    for (int i = 0; i < 16; ++i) {
        const int h = hbase + i;
        const f32x4* wr = (const f32x4*)(W_text + (size_t)h * TEXT_DIM);
        float s = dot4(t0, wr[lane]) + dot4(t1, wr[lane + 64])
                + dot4(t2, wr[lane + 128]);
        #pragma unroll
        for (int off = 32; off; off >>= 1)
            s += __shfl_xor(s, off, 64);
        if (lane == 0)
            t_out[(size_t)b * HIDDEN + h] = s + b_text[h];
    }
}

// ---------------------------------------------------------------------------
// Kernel B: v[b,d] = sum_h t[b,h] * W_patch[h,d]; bias[b] = t[b,:].b_patch
// grid (32 b, 4 d-chunks), 256 threads. t[b] staged in LDS.
// CHANGED vs R2: 8 independent accumulators + unroll 4 -> 32 L2 loads in
// flight per thread (R2's 16 left the h-loop latency-bound at ~200cy/load).
// ---------------------------------------------------------------------------
__global__ __launch_bounds__(256) void fold_kernel(
    const float* __restrict__ t,        // [B, HIDDEN]
    const float* __restrict__ W_patch,  // [HIDDEN, PATCH_DIM]
    const float* __restrict__ b_patch,  // [HIDDEN]
    float* __restrict__ v,              // [B, PATCH_DIM]
    float* __restrict__ bias_out)       // [B]
{
    const int b   = blockIdx.x;
    const int dc  = blockIdx.y;
    const int tid = threadIdx.x;

    __shared__ float t_sh[HIDDEN];
    t_sh[tid]       = t[(size_t)b * HIDDEN + tid];
    t_sh[tid + 256] = t[(size_t)b * HIDDEN + tid + 256];
    __syncthreads();

    const int d = dc * 256 + tid;
    const float* wp = W_patch + d;

    float a0 = 0.f, a1 = 0.f, a2 = 0.f, a3 = 0.f;
    float a4 = 0.f, a5 = 0.f, a6 = 0.f, a7 = 0.f;
    #pragma unroll 4
    for (int h = 0; h < HIDDEN; h += 8) {
        a0 = fmaf(t_sh[h + 0], wp[(size_t)(h + 0) * PATCH_DIM], a0);
        a1 = fmaf(t_sh[h + 1], wp[(size_t)(h + 1) * PATCH_DIM], a1);
        a2 = fmaf(t_sh[h + 2], wp[(size_t)(h + 2) * PATCH_DIM], a2);
        a3 = fmaf(t_sh[h + 3], wp[(size_t)(h + 3) * PATCH_DIM], a3);
        a4 = fmaf(t_sh[h + 4], wp[(size_t)(h + 4) * PATCH_DIM], a4);
        a5 = fmaf(t_sh[h + 5], wp[(size_t)(h + 5) * PATCH_DIM], a5);
        a6 = fmaf(t_sh[h + 6], wp[(size_t)(h + 6) * PATCH_DIM], a6);
        a7 = fmaf(t_sh[h + 7], wp[(size_t)(h + 7) * PATCH_DIM], a7);
    }
    v[(size_t)b * PATCH_DIM + d] =
        ((a0 + a1) + (a2 + a3)) + ((a4 + a5) + (a6 + a7));

    if (dc == 0) {
        float partial = t_sh[tid] * b_patch[tid]
                      + t_sh[tid + 256] * b_patch[tid + 256];
        #pragma unroll
        for (int off = 32; off; off >>= 1)
            partial += __shfl_xor(partial, off, 64);
        __shared__ float wsum[4];
        if ((tid & 63) == 0) wsum[tid >> 6] = partial;
        __syncthreads();
        if (tid == 0)
            bias_out[b] = (wsum[0] + wsum[1]) + (wsum[2] + wsum[3]);
    }
}

// ---------------------------------------------------------------------------
// Kernel C (dominant, streams 512 MB of patches):
//   scores[b,n] = patches[b,n,:] . v[b,:] + bias[b]
// EXACTLY R2's proven structure (112.5us total): 2048 blocks x 4 waves, wave
// owns 16 contiguous rows of one b, v[b] in 16 regs, compiler-scheduled
// 4-row groups, ~100 VGPR -> 5 waves/SIMD (occupancy is the key resource:
// R4's 3-waves/SIMD hand-pipeline regressed 26%).
// SINGLE CHANGE vs R2: plain loads instead of __builtin_nontemporal_load —
// isolating the nt policy, the one untested variable in the 5.25-vs-6.3TB/s
// gap.
// ---------------------------------------------------------------------------
__global__ __launch_bounds__(256) void score_kernel(
    const float* __restrict__ patches,  // [B*N, PATCH_DIM]
    const float* __restrict__ v,        // [B, PATCH_DIM]
    const float* __restrict__ bias,     // [B]
    float* __restrict__ out)            // [B*N]
{
    const int lane = threadIdx.x & 63;
    const int g    = blockIdx.x * 4 + (threadIdx.x >> 6);  // 0..8191
    const int b    = g >> 8;          // 256 waves per b
    const int row0 = g << 4;          // 16 rows per wave

    const f32x4* vv = (const f32x4*)(v + (size_t)b * PATCH_DIM);
    const f32x4 v0 = vv[lane], v1 = vv[lane + 64],
                v2 = vv[lane + 128], v3 = vv[lane + 192];
    const float bs = bias[b];

    for (int i = 0; i < 16; i += 4) {
        const f32x4* p0 = (const f32x4*)(patches + (size_t)(row0 + i + 0) * PATCH_DIM);
        const f32x4* p1 = (const f32x4*)(patches + (size_t)(row0 + i + 1) * PATCH_DIM);
        const f32x4* p2 = (const f32x4*)(patches + (size_t)(row0 + i + 2) * PATCH_DIM);
        const f32x4* p3 = (const f32x4*)(patches + (size_t)(row0 + i + 3) * PATCH_DIM);

        f32x4 a00 = p0[lane];
        f32x4 a01 = p0[lane + 64];
        f32x4 a02 = p0[lane + 128];
        f32x4 a03 = p0[lane + 192];
        f32x4 a10 = p1[lane];
        f32x4 a11 = p1[lane + 64];
        f32x4 a12 = p1[lane + 128];
        f32x4 a13 = p1[lane + 192];
        f32x4 a20 = p2[lane];
        f32x4 a21 = p2[lane + 64];
        f32x4 a22 = p2[lane + 128];
        f32x4 a23 = p2[lane + 192];
        f32x4 a30 = p3[lane];
        f32x4 a31 = p3[lane + 64];
        f32x4 a32 = p3[lane + 128];
        f32x4 a33 = p3[lane + 192];

        float s0 = dot4(a00, v0) + dot4(a01, v1) + dot4(a02, v2) + dot4(a03, v3);
        float s1 = dot4(a10, v0) + dot4(a11, v1) + dot4(a12, v2) + dot4(a13, v3);
        float s2 = dot4(a20, v0) + dot4(a21, v1) + dot4(a22, v2) + dot4(a23, v3);
        float s3 = dot4(a30, v0) + dot4(a31, v1) + dot4(a32, v2) + dot4(a33, v3);

        // 4 independent butterfly chains, interleaved to hide shfl latency
        #pragma unroll
        for (int off = 32; off; off >>= 1) {
            s0 += __shfl_xor(s0, off, 64);
            s1 += __shfl_xor(s1, off, 64);
            s2 += __shfl_xor(s2, off, 64);
            s3 += __shfl_xor(s3, off, 64);
        }

        if (lane == 0) {
            f32x4 o = { s0 + bs, s1 + bs, s2 + bs, s3 + bs };
            *(f32x4*)(out + row0 + i) = o;
        }
    }
}

extern "C" void kernel_launch(void* const* d_in, const int* in_sizes, int n_in,
                              void* d_out, int out_size, void* d_ws, size_t ws_size,
                              hipStream_t stream) {
    const float* patches = (const float*)d_in[0];  // [B, N, PATCH_DIM]
    const float* text    = (const float*)d_in[1];  // [B, TEXT_DIM]
    const float* W_patch = (const float*)d_in[2];  // [HIDDEN, PATCH_DIM]
    const float* b_patch = (const float*)d_in[3];  // [HIDDEN]
    const float* W_text  = (const float*)d_in[4];  // [HIDDEN, TEXT_DIM]
    const float* b_text  = (const float*)d_in[5];  // [HIDDEN]
    float* out = (float*)d_out;                    // [B, N]

    // Workspace layout (floats): t [B*HIDDEN], v [B*PATCH_DIM], bias [B]
    float* t_ws    = (float*)d_ws;
    float* v_ws    = t_ws + B_DIM * HIDDEN;
    float* bias_ws = v_ws + B_DIM * PATCH_DIM;

    text_proj_kernel<<<dim3(B_DIM, 8), 256, 0, stream>>>(text, W_text, b_text, t_ws);
    fold_kernel<<<dim3(B_DIM, 4), 256, 0, stream>>>(t_ws, W_patch, b_patch, v_ws, bias_ws);
    score_kernel<<<2048, 256, 0, stream>>>(patches, v_ws, bias_ws, out);
}